// Round 3
// baseline (81.167 us; speedup 1.0000x reference)
//
#include <hip/hip_runtime.h>

// Problem constants (fixed by the reference):
//   input:  (1, 256, 512, 512) f32
//   state:  (1, 256, 256, 256) f32
//   change: (32768,) i32 flat spatial indices y*W + x
#define C_  256
#define H_  512
#define W_  512
#define OH_ 256
#define OW_ 256
// mask: 1 bit per output spatial pixel -> OH*OW/32 = 2048 u32 = 8 KB (in d_ws)

typedef float f4 __attribute__((ext_vector_type(4)));
typedef float f2 __attribute__((ext_vector_type(2)));

__device__ __forceinline__ f4 ntload4(const float* p) {
    return __builtin_nontemporal_load(reinterpret_cast<const f4*>(p));
}
__device__ __forceinline__ f2 ntload2(const float* p) {
    return __builtin_nontemporal_load(reinterpret_cast<const f2*>(p));
}
__device__ __forceinline__ void ntstore2(float* p, f2 v) {
    __builtin_nontemporal_store(v, reinterpret_cast<f2*>(p));
}

__global__ void cbpool_set_mask(const int* __restrict__ change, int K,
                                unsigned int* __restrict__ mask) {
    int k = blockIdx.x * blockDim.x + threadIdx.x;
    if (k >= K) return;
    int idx = change[k];
    int y = idx >> 9;            // W = 512 = 2^9
    int x = idx & (W_ - 1);
    int bit = (y >> 1) * OW_ + (x >> 1);
    atomicOr(&mask[bit >> 5], 1u << (bit & 31));
}

// One thread per 4x2 block of output pixels (4 output rows x 2 cols).
// Input: 8 rows x 16 B/lane, lane-stride 16 B -> every dwordx4 load is a
// fully dense 1 KB/warp transaction (full 64-B line coverage, min requests).
// State/out: dense float2 (512 B/warp/instr). All bulk traffic non-temporal.
__global__ void __launch_bounds__(256)
cbpool_fused(const float* __restrict__ in,
             const float* __restrict__ state,
             const unsigned int* __restrict__ mask,
             float* __restrict__ out) {
    int tid = blockIdx.x * blockDim.x + threadIdx.x;   // 0 .. C*(OH/4)*(OW/2)-1
    int p   = tid & 127;               // output col-pair, ox = 2p
    int oyb = (tid >> 7) & 63;         // block of 4 output rows
    int c   = tid >> 13;               // channel

    // input base: c*H*W + (8*oyb)*W + 4*p
    const float* ib = in + ((size_t)c << 18) + ((size_t)oyb << 12) + (p << 2);
    f4 L0 = ntload4(ib);
    f4 L1 = ntload4(ib + 1 * W_);
    f4 L2 = ntload4(ib + 2 * W_);
    f4 L3 = ntload4(ib + 3 * W_);
    f4 L4 = ntload4(ib + 4 * W_);
    f4 L5 = ntload4(ib + 5 * W_);
    f4 L6 = ntload4(ib + 6 * W_);
    f4 L7 = ntload4(ib + 7 * W_);

    // state/out base: c*OH*OW + (4*oyb)*OW + 2*p
    size_t ob = ((size_t)c << 16) + ((size_t)oyb << 10) + (p << 1);
    f2 s0 = ntload2(state + ob);
    f2 s1 = ntload2(state + ob + 1 * OW_);
    f2 s2 = ntload2(state + ob + 2 * OW_);
    f2 s3 = ntload2(state + ob + 3 * OW_);

    // mask words: bit = (4*oyb + r)*256 + 2*p  -> word = (4*oyb+r)*8 + (p>>4)
    int mw = (oyb << 5) + (p >> 4);
    unsigned int m0 = mask[mw];
    unsigned int m1 = mask[mw + 8];
    unsigned int m2 = mask[mw + 16];
    unsigned int m3 = mask[mw + 24];
    int sh = (p << 1) & 31;

    f2 o0, o1, o2, o3;
    o0.x = ((m0 >> sh) & 1u)       ? fmaxf(fmaxf(L0.x, L0.y), fmaxf(L1.x, L1.y)) : s0.x;
    o0.y = ((m0 >> (sh + 1)) & 1u) ? fmaxf(fmaxf(L0.z, L0.w), fmaxf(L1.z, L1.w)) : s0.y;
    o1.x = ((m1 >> sh) & 1u)       ? fmaxf(fmaxf(L2.x, L2.y), fmaxf(L3.x, L3.y)) : s1.x;
    o1.y = ((m1 >> (sh + 1)) & 1u) ? fmaxf(fmaxf(L2.z, L2.w), fmaxf(L3.z, L3.w)) : s1.y;
    o2.x = ((m2 >> sh) & 1u)       ? fmaxf(fmaxf(L4.x, L4.y), fmaxf(L5.x, L5.y)) : s2.x;
    o2.y = ((m2 >> (sh + 1)) & 1u) ? fmaxf(fmaxf(L4.z, L4.w), fmaxf(L5.z, L5.w)) : s2.y;
    o3.x = ((m3 >> sh) & 1u)       ? fmaxf(fmaxf(L6.x, L6.y), fmaxf(L7.x, L7.y)) : s3.x;
    o3.y = ((m3 >> (sh + 1)) & 1u) ? fmaxf(fmaxf(L6.z, L6.w), fmaxf(L7.z, L7.w)) : s3.y;

    ntstore2(out + ob,            o0);
    ntstore2(out + ob + 1 * OW_,  o1);
    ntstore2(out + ob + 2 * OW_,  o2);
    ntstore2(out + ob + 3 * OW_,  o3);
}

extern "C" void kernel_launch(void* const* d_in, const int* in_sizes, int n_in,
                              void* d_out, int out_size, void* d_ws, size_t ws_size,
                              hipStream_t stream) {
    const float* in     = (const float*)d_in[0];
    const float* state  = (const float*)d_in[1];
    const int*   change = (const int*)d_in[2];
    float*       out    = (float*)d_out;
    unsigned int* mask  = (unsigned int*)d_ws;   // 8 KB used

    const int K = in_sizes[2];

    hipMemsetAsync(mask, 0, (OH_ * OW_ / 32) * sizeof(unsigned int), stream);
    cbpool_set_mask<<<(K + 255) / 256, 256, 0, stream>>>(change, K, mask);

    const int total_threads = C_ * (OH_ / 4) * (OW_ / 2);   // 2,097,152
    cbpool_fused<<<total_threads / 256, 256, 0, stream>>>(in, state, mask, out);
}

// Round 4
// 77.690 us; speedup vs baseline: 1.0448x; 1.0448x over previous
//
#include <hip/hip_runtime.h>

// Problem constants (fixed by the reference):
//   input:  (1, 256, 512, 512) f32
//   state:  (1, 256, 256, 256) f32
//   change: (32768,) i32 flat spatial indices y*W + x
#define C_  256
#define H_  512
#define W_  512
#define OH_ 256
#define OW_ 256
// mask: 1 bit per output spatial pixel -> OH*OW/32 = 2048 u32 = 8 KB (in d_ws)

typedef float f4 __attribute__((ext_vector_type(4)));

__device__ __forceinline__ f4 ntload4(const float* p) {
    return __builtin_nontemporal_load(reinterpret_cast<const f4*>(p));
}
__device__ __forceinline__ void ntstore4(float* p, f4 v) {
    __builtin_nontemporal_store(v, reinterpret_cast<f4*>(p));
}

// Single-workgroup mask builder: clear in LDS, scatter via LDS atomics,
// dump 8 KB to global. Replaces hipMemsetAsync + global-atomic kernel
// (one dispatch instead of two, no global atomics).
__global__ void __launch_bounds__(256)
cbpool_build_mask(const int* __restrict__ change, int K,
                  unsigned int* __restrict__ mask) {
    __shared__ unsigned int lmask[OH_ * OW_ / 32];   // 2048 words = 8 KB
    for (int i = threadIdx.x; i < OH_ * OW_ / 32; i += 256)
        lmask[i] = 0u;
    __syncthreads();
    const int4* c4 = reinterpret_cast<const int4*>(change);
    for (int k = threadIdx.x; k < K / 4; k += 256) {
        int4 v = c4[k];
        #pragma unroll
        for (int j = 0; j < 4; ++j) {
            int idx = (j == 0) ? v.x : (j == 1) ? v.y : (j == 2) ? v.z : v.w;
            int y = idx >> 9;            // W = 512 = 2^9
            int x = idx & (W_ - 1);
            int bit = (y >> 1) * OW_ + (x >> 1);
            atomicOr(&lmask[bit >> 5], 1u << (bit & 31));
        }
    }
    __syncthreads();
    for (int i = threadIdx.x; i < OH_ * OW_ / 32; i += 256)
        mask[i] = lmask[i];
}

// One thread per 2x4 block of output pixels (2 output rows x 4 cols).
// Input: 4 rows x 32 B/thread (two dwordx4 per row, 32B lane stride pairs) —
// round-2 pattern, which beat the "dense" 16B-stride layout. State/out stay
// full float4 width. All bulk traffic non-temporal (streamed once, >> LLC).
__global__ void __launch_bounds__(256)
cbpool_fused(const float* __restrict__ in,
             const float* __restrict__ state,
             const unsigned int* __restrict__ mask,
             float* __restrict__ out) {
    int tid = blockIdx.x * blockDim.x + threadIdx.x;   // 0 .. C*(OH/2)*(OW/4)-1
    int q   = tid & 63;                // col quad, ox = 4q
    int oyp = (tid >> 6) & 127;        // output row pair, oy = 2*oyp
    int c   = tid >> 13;               // channel

    // input base: c*H*W + (4*oyp)*W + 8*q
    const float* ib = in + ((size_t)c << 18) + ((size_t)oyp << 11) + (q << 3);
    f4 L0a = ntload4(ib);
    f4 L0b = ntload4(ib + 4);
    f4 L1a = ntload4(ib + W_);
    f4 L1b = ntload4(ib + W_ + 4);
    f4 L2a = ntload4(ib + 2 * W_);
    f4 L2b = ntload4(ib + 2 * W_ + 4);
    f4 L3a = ntload4(ib + 3 * W_);
    f4 L3b = ntload4(ib + 3 * W_ + 4);

    // state/out base: c*OH*OW + (2*oyp)*OW + 4*q
    size_t ob = ((size_t)c << 16) + ((size_t)oyp << 9) + (q << 2);
    f4 s0 = ntload4(state + ob);
    f4 s1 = ntload4(state + ob + OW_);

    // mask: bit(row 2*oyp) = (2*oyp)*256 + 4q -> word = oyp*16 + (q>>3)
    int mw = (oyp << 4) + (q >> 3);
    unsigned int m0 = mask[mw];
    unsigned int m1 = mask[mw + 8];
    int sh = (q << 2) & 31;

    f4 p0, p1;
    p0.x = fmaxf(fmaxf(L0a.x, L0a.y), fmaxf(L1a.x, L1a.y));
    p0.y = fmaxf(fmaxf(L0a.z, L0a.w), fmaxf(L1a.z, L1a.w));
    p0.z = fmaxf(fmaxf(L0b.x, L0b.y), fmaxf(L1b.x, L1b.y));
    p0.w = fmaxf(fmaxf(L0b.z, L0b.w), fmaxf(L1b.z, L1b.w));
    p1.x = fmaxf(fmaxf(L2a.x, L2a.y), fmaxf(L3a.x, L3a.y));
    p1.y = fmaxf(fmaxf(L2a.z, L2a.w), fmaxf(L3a.z, L3a.w));
    p1.z = fmaxf(fmaxf(L2b.x, L2b.y), fmaxf(L3b.x, L3b.y));
    p1.w = fmaxf(fmaxf(L2b.z, L2b.w), fmaxf(L3b.z, L3b.w));

    f4 o0, o1;
    o0.x = ((m0 >> (sh + 0)) & 1u) ? p0.x : s0.x;
    o0.y = ((m0 >> (sh + 1)) & 1u) ? p0.y : s0.y;
    o0.z = ((m0 >> (sh + 2)) & 1u) ? p0.z : s0.z;
    o0.w = ((m0 >> (sh + 3)) & 1u) ? p0.w : s0.w;
    o1.x = ((m1 >> (sh + 0)) & 1u) ? p1.x : s1.x;
    o1.y = ((m1 >> (sh + 1)) & 1u) ? p1.y : s1.y;
    o1.z = ((m1 >> (sh + 2)) & 1u) ? p1.z : s1.z;
    o1.w = ((m1 >> (sh + 3)) & 1u) ? p1.w : s1.w;

    ntstore4(out + ob,       o0);
    ntstore4(out + ob + OW_, o1);
}

extern "C" void kernel_launch(void* const* d_in, const int* in_sizes, int n_in,
                              void* d_out, int out_size, void* d_ws, size_t ws_size,
                              hipStream_t stream) {
    const float* in     = (const float*)d_in[0];
    const float* state  = (const float*)d_in[1];
    const int*   change = (const int*)d_in[2];
    float*       out    = (float*)d_out;
    unsigned int* mask  = (unsigned int*)d_ws;   // 8 KB used

    const int K = in_sizes[2];

    cbpool_build_mask<<<1, 256, 0, stream>>>(change, K, mask);

    const int total_threads = C_ * (OH_ / 2) * (OW_ / 4);   // 2,097,152
    cbpool_fused<<<total_threads / 256, 256, 0, stream>>>(in, state, mask, out);
}

// Round 5
// 72.139 us; speedup vs baseline: 1.1252x; 1.0770x over previous
//
#include <hip/hip_runtime.h>

// Problem constants (fixed by the reference):
//   input:  (1, 256, 512, 512) f32
//   state:  (1, 256, 256, 256) f32
//   change: (32768,) i32 flat spatial indices y*W + x
#define C_  256
#define H_  512
#define W_  512
#define OH_ 256
#define OW_ 256
// mask: 1 bit per output spatial pixel -> OH*OW/32 = 2048 u32 = 8 KB (in d_ws)

typedef float f4 __attribute__((ext_vector_type(4)));

__device__ __forceinline__ f4 ntload4(const float* p) {
    return __builtin_nontemporal_load(reinterpret_cast<const f4*>(p));
}
__device__ __forceinline__ void ntstore4(float* p, f4 v) {
    __builtin_nontemporal_store(v, reinterpret_cast<f4*>(p));
}

// Single-workgroup mask builder, 1024 threads (16 waves on one CU) to hide
// the 128 KB index-fetch latency. Clear LDS, scatter via LDS atomics, dump
// 8 KB to global. One dispatch, no global atomics, no memset.
__global__ void __launch_bounds__(1024)
cbpool_build_mask(const int* __restrict__ change, int K,
                  unsigned int* __restrict__ mask) {
    __shared__ unsigned int lmask[OH_ * OW_ / 32];   // 2048 words = 8 KB
    for (int i = threadIdx.x; i < OH_ * OW_ / 32; i += 1024)
        lmask[i] = 0u;
    __syncthreads();
    const int4* c4 = reinterpret_cast<const int4*>(change);
    for (int k = threadIdx.x; k < K / 4; k += 1024) {
        int4 v = c4[k];
        #pragma unroll
        for (int j = 0; j < 4; ++j) {
            int idx = (j == 0) ? v.x : (j == 1) ? v.y : (j == 2) ? v.z : v.w;
            int y = idx >> 9;            // W = 512 = 2^9
            int x = idx & (W_ - 1);
            int bit = (y >> 1) * OW_ + (x >> 1);
            atomicOr(&lmask[bit >> 5], 1u << (bit & 31));
        }
    }
    __syncthreads();
    for (int i = threadIdx.x; i < OH_ * OW_ / 32; i += 1024)
        mask[i] = lmask[i];
}

// Round-2 fused kernel (best so far): one thread per QUAD of horizontally-
// adjacent output pixels. 4x dwordx4 input, f4 state, f4 out, 1 mask word.
// All bulk traffic non-temporal (streamed once, working set >> LLC).
__global__ void __launch_bounds__(256)
cbpool_fused(const float* __restrict__ in,
             const float* __restrict__ state,
             const unsigned int* __restrict__ mask,
             float* __restrict__ out) {
    int tid = blockIdx.x * blockDim.x + threadIdx.x;   // 0 .. C*OH*(OW/4)-1
    int q  = tid & 63;                 // quad index along output row, 0..63
    int oy = (tid >> 6) & (OH_ - 1);   // output row
    int c  = tid >> 14;                // channel

    // input row pair base: c*H*W + (2*oy)*W + 8*q
    const float* inrow = in + ((size_t)c << 18) + ((size_t)oy << 10) + (q << 3);
    f4 a0 = ntload4(inrow);
    f4 a1 = ntload4(inrow + 4);
    f4 b0 = ntload4(inrow + W_);
    f4 b1 = ntload4(inrow + W_ + 4);

    f4 pooled;
    pooled.x = fmaxf(fmaxf(a0.x, a0.y), fmaxf(b0.x, b0.y));
    pooled.y = fmaxf(fmaxf(a0.z, a0.w), fmaxf(b0.z, b0.w));
    pooled.z = fmaxf(fmaxf(a1.x, a1.y), fmaxf(b1.x, b1.y));
    pooled.w = fmaxf(fmaxf(a1.z, a1.w), fmaxf(b1.z, b1.w));

    size_t obase = ((size_t)c << 16) + (oy << 8) + (q << 2);
    f4 s = ntload4(state + obase);

    unsigned int m = mask[(oy << 3) + (q >> 3)];   // 4 bits for this quad share a word
    int sh = (q << 2) & 31;

    f4 o;
    o.x = ((m >> (sh + 0)) & 1u) ? pooled.x : s.x;
    o.y = ((m >> (sh + 1)) & 1u) ? pooled.y : s.y;
    o.z = ((m >> (sh + 2)) & 1u) ? pooled.z : s.z;
    o.w = ((m >> (sh + 3)) & 1u) ? pooled.w : s.w;
    ntstore4(out + obase, o);
}

extern "C" void kernel_launch(void* const* d_in, const int* in_sizes, int n_in,
                              void* d_out, int out_size, void* d_ws, size_t ws_size,
                              hipStream_t stream) {
    const float* in     = (const float*)d_in[0];
    const float* state  = (const float*)d_in[1];
    const int*   change = (const int*)d_in[2];
    float*       out    = (float*)d_out;
    unsigned int* mask  = (unsigned int*)d_ws;   // 8 KB used

    const int K = in_sizes[2];

    cbpool_build_mask<<<1, 1024, 0, stream>>>(change, K, mask);

    const int total_quads = C_ * OH_ * (OW_ / 4);      // 4,194,304
    cbpool_fused<<<total_quads / 256, 256, 0, stream>>>(in, state, mask, out);
}